// Round 6
// baseline (380.960 us; speedup 1.0000x reference)
//
#include <hip/hip_runtime.h>
#include <hip/hip_bf16.h>

#define GD 64
#define GC 256

typedef unsigned short u16;
typedef unsigned int u32;
typedef short bf16x8 __attribute__((ext_vector_type(8)));
typedef float f32x4 __attribute__((ext_vector_type(4)));

__device__ __forceinline__ u16 f2bf_rne(float f) {
    u32 u = __builtin_bit_cast(u32, f);
    u = (u + 0x7FFFu + ((u >> 16) & 1u)) >> 16;
    return (u16)u;
}

// round f32 to the exact bf16-representable value (RNE)
__device__ __forceinline__ float bfval(float f) {
    u32 u = __builtin_bit_cast(u32, f);
    u = (u + 0x7FFFu + ((u >> 16) & 1u)) & 0xFFFF0000u;
    return __builtin_bit_cast(float, u);
}

__device__ __forceinline__ void unpack8(uint4 r, float* w) {
    u32 v[4] = {r.x, r.y, r.z, r.w};
#pragma unroll
    for (int i = 0; i < 4; i++) {
        w[2 * i]     = __builtin_bit_cast(float, v[i] << 16);
        w[2 * i + 1] = __builtin_bit_cast(float, v[i] & 0xFFFF0000u);
    }
}

// ---------------------------------------------------------------- init/build map
__global__ __launch_bounds__(256) void init_map(uint4* __restrict__ m) {
    int i = blockIdx.x * 256 + threadIdx.x;        // 65536 uint4 = 1 MB
    uint4 v;
    v.x = v.y = v.z = v.w = 0xFFFFFFFFu;
    m[i] = v;
}

__global__ __launch_bounds__(256) void build_map(const int* __restrict__ coords,
        int* __restrict__ map, int n) {
    int i = blockIdx.x * 256 + threadIdx.x;
    if (i < n) {
        int ix = coords[3 * i], iy = coords[3 * i + 1], iz = coords[3 * i + 2];
        map[(ix * GD + iy) * GD + iz] = i;         // coords unique (permutation)
    }
}

// 4 outputs (window 7, 10 inputs v[0..9]) via shared pair maxes:
// 5 pairs + 3 maxes per output = 17 fmax per channel.
// Results packed to bf16 pairs into q[d][slot].
__device__ __forceinline__ void max4pack(const float (&v)[10][8], u32 (&q)[4][4]) {
#pragma unroll
    for (int i = 0; i < 4; i++) {
        u32 h[4][2];
#pragma unroll
        for (int hh = 0; hh < 2; hh++) {
            int ch = 2 * i + hh;
            float p0 = fmaxf(v[0][ch], v[1][ch]);
            float p2 = fmaxf(v[2][ch], v[3][ch]);
            float p4 = fmaxf(v[4][ch], v[5][ch]);
            float p6 = fmaxf(v[6][ch], v[7][ch]);
            float p8 = fmaxf(v[8][ch], v[9][ch]);
            float o0 = fmaxf(fmaxf(p0, p2), fmaxf(p4, v[6][ch]));        // v0..v6
            float o1 = fmaxf(fmaxf(v[1][ch], p2), fmaxf(p4, p6));        // v1..v7
            float o2 = fmaxf(fmaxf(p2, p4), fmaxf(p6, v[8][ch]));        // v2..v8
            float o3 = fmaxf(fmaxf(v[3][ch], p4), fmaxf(p6, p8));        // v3..v9
            h[0][hh] = __builtin_bit_cast(u32, o0);
            h[1][hh] = __builtin_bit_cast(u32, o1);
            h[2][hh] = __builtin_bit_cast(u32, o2);
            h[3][hh] = __builtin_bit_cast(u32, o3);
        }
#pragma unroll
        for (int d = 0; d < 4; d++)
            q[d][i] = (h[d][0] >> 16) | (h[d][1] & 0xFFFF0000u);
    }
}

// ---------------------------------------------------------------- z pool (gather)
// Chain-free: each 32-lane group computes 4 consecutive z outputs from 10
// independent feats-row gathers (straight-line loads, no loop-carried window).
__global__ __launch_bounds__(256, 3) void pool_z_gather(const float* __restrict__ feats,
        const int* __restrict__ map, u16* __restrict__ grid) {
    int lane = threadIdx.x & 31;
    int gid = blockIdx.x * 8 + (threadIdx.x >> 5);   // 0..65535
    int L = gid >> 4;                                 // line = x*64+y
    int a0 = (gid & 15) << 2;                         // first output z
    const int* mrow = map + L * GD;
    const float* fb = feats + lane * 8;
    u16* po = grid + ((size_t)L * GD + a0) * GC + lane * 8;

    int mi[10];
#pragma unroll
    for (int i = 0; i < 10; i++) {                    // 10 independent map loads
        int w = a0 - 3 + i;
        int wc = min(max(w, 0), 63);
        int m = mrow[wc];
        mi[i] = ((unsigned)w < 64u) ? m : -1;
    }

    float4 fa[10], fbb[10];
#pragma unroll
    for (int i = 0; i < 10; i++) {                    // 20 independent feats loads
        const float4* f4 = (const float4*)(fb + (size_t)max(mi[i], 0) * GC);
        fa[i] = f4[0];
        fbb[i] = f4[1];
    }
    asm volatile("" ::: "memory");                    // keep loads above compute

    float v[10][8];
#pragma unroll
    for (int i = 0; i < 10; i++) {
        bool s = mi[i] >= 0;
        v[i][0] = bfval(s ? fa[i].x : -INFINITY);
        v[i][1] = bfval(s ? fa[i].y : -INFINITY);
        v[i][2] = bfval(s ? fa[i].z : -INFINITY);
        v[i][3] = bfval(s ? fa[i].w : -INFINITY);
        v[i][4] = bfval(s ? fbb[i].x : -INFINITY);
        v[i][5] = bfval(s ? fbb[i].y : -INFINITY);
        v[i][6] = bfval(s ? fbb[i].z : -INFINITY);
        v[i][7] = bfval(s ? fbb[i].w : -INFINITY);
    }

    u32 q[4][4];
    max4pack(v, q);
#pragma unroll
    for (int d = 0; d < 4; d++)                       // 4 contiguous 512-B stores
        *(uint4*)(po + (size_t)d * GC) = make_uint4(q[d][0], q[d][1], q[d][2], q[d][3]);
}

// ---------------------------------------------------------------- y pool (dense)
__global__ __launch_bounds__(256, 3) void pool_y(const u16* __restrict__ gin,
        u16* __restrict__ gout) {
    int lane = threadIdx.x & 31;
    int gid = blockIdx.x * 8 + (threadIdx.x >> 5);   // 0..65535
    int L = gid >> 4;                                 // line = x*64+z
    int a0 = (gid & 15) << 2;                         // first output y
    int x = L >> 6, z = L & 63;
    size_t base = ((size_t)x * GD * GD + z) * GC + lane * 8;
    const size_t st = (size_t)GD * GC;                // +1 in y
    const u16* pin = gin + base;
    u16* po = gout + base + (size_t)a0 * st;

    uint4 c[10];
#pragma unroll
    for (int i = 0; i < 10; i++) {                    // 10 independent loads
        int wc = min(max(a0 - 3 + i, 0), 63);
        c[i] = *(const uint4*)(pin + (size_t)wc * st);
    }
    asm volatile("" ::: "memory");

    float v[10][8];
#pragma unroll
    for (int i = 0; i < 10; i++) {
        float t[8];
        unpack8(c[i], t);
        bool ok = (unsigned)(a0 - 3 + i) < 64u;
#pragma unroll
        for (int ch = 0; ch < 8; ch++) v[i][ch] = ok ? t[ch] : -INFINITY;
    }

    u32 q[4][4];
    max4pack(v, q);
#pragma unroll
    for (int d = 0; d < 4; d++)
        *(uint4*)(po + (size_t)d * st) = make_uint4(q[d][0], q[d][1], q[d][2], q[d][3]);
}

// ---------------------------------------------------------------- x pool + compact
__global__ __launch_bounds__(256, 3) void pool_x_compact(const u16* __restrict__ gin,
        const int* __restrict__ map, u16* __restrict__ P) {
    int lane = threadIdx.x & 31;
    int gid = blockIdx.x * 8 + (threadIdx.x >> 5);   // 0..65535
    int L = gid >> 4;                                 // line = y*64+z
    int a0 = (gid & 15) << 2;                         // first output x
    size_t base = (size_t)L * GC + lane * 8;
    const size_t st = (size_t)GD * GD * GC;           // +1 in x
    const u16* pin = gin + base;

    int mo[4];
#pragma unroll
    for (int d = 0; d < 4; d++)                       // gating map entries
        mo[d] = map[(size_t)(a0 + d) * GD * GD + L];

    uint4 c[10];
#pragma unroll
    for (int i = 0; i < 10; i++) {
        int wc = min(max(a0 - 3 + i, 0), 63);
        c[i] = *(const uint4*)(pin + (size_t)wc * st);
    }
    asm volatile("" ::: "memory");

    float v[10][8];
#pragma unroll
    for (int i = 0; i < 10; i++) {
        float t[8];
        unpack8(c[i], t);
        bool ok = (unsigned)(a0 - 3 + i) < 64u;
#pragma unroll
        for (int ch = 0; ch < 8; ch++) v[i][ch] = ok ? t[ch] : -INFINITY;
    }

    u32 q[4][4];
    max4pack(v, q);
#pragma unroll
    for (int d = 0; d < 4; d++) {
        if (mo[d] >= 0)
            *(uint4*)(P + (size_t)mo[d] * GC + lane * 8) =
                make_uint4(q[d][0], q[d][1], q[d][2], q[d][3]);
    }
}

// ---------------------------------------------------------------- weight prep
__global__ __launch_bounds__(256) void prep_weights(const float* __restrict__ W1,
        const float* __restrict__ W2, u16* __restrict__ img1, u16* __restrict__ img2) {
    int t = blockIdx.x * 256 + threadIdx.x;   // 0..65535
    if (t < 32768) {
        int h = t >> 14, nn = (t >> 8) & 63, chunk = (t >> 3) & 31, j = t & 7;
        int k = chunk * 8 + j;
        img1[(h << 14) + nn * 256 + (((chunk ^ (nn & 7)) << 3) | j)] =
            f2bf_rne(W1[k * 128 + h * 64 + nn]);
    } else {
        int t2 = t - 32768;
        int h = t2 >> 14, nn = (t2 >> 7) & 127, chunk = (t2 >> 3) & 15, j = t2 & 7;
        int k = chunk * 8 + j;
        img2[(h << 14) + nn * 128 + (((chunk ^ (nn & 7)) << 3) | j)] =
            f2bf_rne(W2[k * 256 + h * 128 + nn]);
    }
}

// ---------------------------------------------------------------- GEMM1 (half-N)
__global__ __launch_bounds__(256, 4) void gemm1_kernel(const u16* __restrict__ P,
        const u16* __restrict__ img1, u16* __restrict__ H, int n, int nrb) {
    __shared__ __align__(16) u16 w1t[64 * 256];   // 32768 B; reused as hbuf
    int h = blockIdx.x >= nrb;
    int rb = blockIdx.x - (h ? nrb : 0);
    int tid = threadIdx.x;

    const uint4* src = (const uint4*)(img1 + (h << 14));
    uint4* dst = (uint4*)w1t;
#pragma unroll
    for (int i = 0; i < 8; i++) dst[i * 256 + tid] = src[i * 256 + tid];

    int wave = tid >> 6, lane = tid & 63, m16 = lane & 15, quad = lane >> 4;
    int row_a = rb * 64 + wave * 16 + m16;
    int ra = min(row_a, n - 1);
    const u16* yrow = P + (size_t)ra * GC;
    bf16x8 afr[8];
#pragma unroll
    for (int kk = 0; kk < 8; kk++)
        afr[kk] = *(const bf16x8*)(yrow + kk * 32 + quad * 8);
    __syncthreads();

    f32x4 acc[4];
#pragma unroll
    for (int t = 0; t < 4; t++) acc[t] = (f32x4){0.f, 0.f, 0.f, 0.f};
#pragma unroll
    for (int kk = 0; kk < 8; kk++) {
        int chunk = kk * 4 + quad;
#pragma unroll
        for (int t = 0; t < 4; t++) {
            int r = t * 16 + m16;
            bf16x8 b = *(const bf16x8*)&w1t[r * 256 + ((chunk ^ (r & 7)) << 3)];
            acc[t] = __builtin_amdgcn_mfma_f32_16x16x32_bf16(afr[kk], b, acc[t], 0, 0, 0);
        }
    }
    __syncthreads();   // w1t dead; reuse as hbuf

    u16* hbuf = w1t;
#pragma unroll
    for (int t = 0; t < 4; t++) {
        int col = t * 16 + m16;
        int c8 = col >> 3, j = col & 7;
#pragma unroll
        for (int rr = 0; rr < 4; rr++) {
            int row_l = wave * 16 + quad * 4 + rr;
            float hv = fmaxf(acc[t][rr], 0.0f);
            hbuf[row_l * 64 + (((c8 ^ (row_l & 7)) << 3) | j)] = f2bf_rne(hv);
        }
    }
    __syncthreads();
#pragma unroll
    for (int i = 0; i < 2; i++) {
        int cid = i * 256 + tid;            // 0..511 chunks of 8
        int row_l = cid >> 3, c8 = cid & 7;
        int grow = rb * 64 + row_l;
        if (grow < n) {
            bf16x8 v = *(const bf16x8*)&hbuf[row_l * 64 + ((c8 ^ (row_l & 7)) << 3)];
            *(bf16x8*)&H[(size_t)grow * 128 + h * 64 + c8 * 8] = v;
        }
    }
}

// ---------------------------------------------------------------- GEMM2 (half-N)
__global__ __launch_bounds__(256, 4) void gemm2_kernel(const u16* __restrict__ H,
        const u16* __restrict__ img2, const float* __restrict__ feats,
        float* __restrict__ out, int n, int nrb) {
    __shared__ __align__(16) char smem[64 * 140 * 4];   // 35840 B
    u16* w2t = (u16*)smem;
    float* zbuf = (float*)smem;
    int h = blockIdx.x >= nrb;
    int rb = blockIdx.x - (h ? nrb : 0);
    int tid = threadIdx.x;

    const uint4* src = (const uint4*)(img2 + (h << 14));
    uint4* dst = (uint4*)w2t;
#pragma unroll
    for (int i = 0; i < 8; i++) dst[i * 256 + tid] = src[i * 256 + tid];

    int wave = tid >> 6, lane = tid & 63, m16 = lane & 15, quad = lane >> 4;
    int row_a = rb * 64 + wave * 16 + m16;
    int ra = min(row_a, n - 1);
    const u16* hrow = H + (size_t)ra * 128;
    bf16x8 afr[4];
#pragma unroll
    for (int kk = 0; kk < 4; kk++)
        afr[kk] = *(const bf16x8*)(hrow + kk * 32 + quad * 8);
    __syncthreads();

    f32x4 acc[8];
#pragma unroll
    for (int t = 0; t < 8; t++) acc[t] = (f32x4){0.f, 0.f, 0.f, 0.f};
#pragma unroll
    for (int kk = 0; kk < 4; kk++) {
        int chunk = kk * 4 + quad;
#pragma unroll
        for (int t = 0; t < 8; t++) {
            int nn = t * 16 + m16;
            bf16x8 b = *(const bf16x8*)&w2t[nn * 128 + ((chunk ^ (nn & 7)) << 3)];
            acc[t] = __builtin_amdgcn_mfma_f32_16x16x32_bf16(afr[kk], b, acc[t], 0, 0, 0);
        }
    }
    __syncthreads();   // w2t dead; write logits into zbuf

#pragma unroll
    for (int t = 0; t < 8; t++) {
        int col = t * 16 + m16;
#pragma unroll
        for (int rr = 0; rr < 4; rr++) {
            int row_l = wave * 16 + quad * 4 + rr;
            zbuf[row_l * 140 + col] = acc[t][rr];
        }
    }
    __syncthreads();
#pragma unroll
    for (int i = 0; i < 8; i++) {
        int f = i * 256 + tid;              // 0..2047 float4s
        int row_l = f >> 5, c4 = f & 31;
        int grow = rb * 64 + row_l;
        if (grow < n) {
            f32x4 z = *(const f32x4*)&zbuf[row_l * 140 + c4 * 4];
            size_t o = (size_t)grow * 256 + h * 128 + c4 * 4;
            f32x4 ft = *(const f32x4*)&feats[o];
            f32x4 r;
#pragma unroll
            for (int c = 0; c < 4; c++)
                r[c] = ft[c] / (1.0f + __expf(-z[c]));
            *(f32x4*)&out[o] = r;
        }
    }
}

// ---------------------------------------------------------------- launch
extern "C" void kernel_launch(void* const* d_in, const int* in_sizes, int n_in,
                              void* d_out, int out_size, void* d_ws, size_t ws_size,
                              hipStream_t stream) {
    const float* feats = (const float*)d_in[0];
    const int* coords = (const int*)d_in[1];
    const float* W1 = (const float*)d_in[2];
    const float* W2 = (const float*)d_in[3];
    float* out = (float*)d_out;

    int n = in_sizes[1] / 3;                       // 100000 points

    size_t grid_bytes = (size_t)GD * GD * GD * GC * 2;          // 134,217,728
    size_t P_bytes = (size_t)n * GC * 2;                        //  51,200,000
    size_t H_bytes = (size_t)n * 128 * 2;                       //  25,600,000
    u16* grid = (u16*)d_ws;                                     // never initialized
    u16* grid2 = (u16*)((char*)d_ws + grid_bytes);              // y-pass output
    u16* P = (u16*)((char*)d_ws + 2 * grid_bytes);
    u16* H = (u16*)((char*)d_ws + 2 * grid_bytes + P_bytes);
    int* map = (int*)((char*)d_ws + 2 * grid_bytes + P_bytes + H_bytes);
    u16* img1 = (u16*)((char*)map + (size_t)GD * GD * GD * 4);  // +1 MB
    u16* img2 = img1 + 32768;

    init_map<<<256, 256, 0, stream>>>((uint4*)map);
    prep_weights<<<256, 256, 0, stream>>>(W1, W2, img1, img2);
    build_map<<<(n + 255) / 256, 256, 0, stream>>>(coords, map, n);

    pool_z_gather<<<8192, 256, 0, stream>>>(feats, map, grid);     // z (chain-free)
    pool_y<<<8192, 256, 0, stream>>>(grid, grid2);                 // y (chain-free)
    pool_x_compact<<<8192, 256, 0, stream>>>(grid2, map, P);       // x -> compact

    int nrb = (n + 63) / 64;
    gemm1_kernel<<<2 * nrb, 256, 0, stream>>>(P, img1, H, n, nrb);
    gemm2_kernel<<<2 * nrb, 256, 0, stream>>>(H, img2, feats, out, n, nrb);
}